// Round 1
// baseline (3985.447 us; speedup 1.0000x reference)
//
#include <hip/hip_runtime.h>

#define BB 8192
#define TT 40
#define HH 128
#define CC 102

__device__ __forceinline__ float sigmoidf_(float x) { return 1.f / (1.f + __expf(-x)); }
__device__ __forceinline__ float tanhf_(float x) { float e = __expf(2.f * x); return 1.f - 2.f / (e + 1.f); }

// One GEMM pass: acc[4][4] += in[32x128 (stride 132)] @ W[128x128]^T restricted to
// this thread's 4 batch rows (brow*4+i) x 4 output cols (ocol*4+j).
// W is staged through LDS transposed (k-major) in two 64-wide k chunks.
__device__ __forceinline__ void gemm_pass(
    const float* __restrict__ in,     // base of [32][132] tile
    const float* __restrict__ Wrows,  // W + ro*HH  (rows ro..ro+127)
    float acc[4][4], float* sWt, int tid, int ocol, int brow)
{
#pragma unroll 1
    for (int kc = 0; kc < 2; ++kc) {
        __syncthreads();
        // stage W[o][kc*64 + k] -> sWt[k][o]  (8192 floats)
#pragma unroll
        for (int q = 0; q < 8; ++q) {
            int f4 = tid + 256 * q;       // 0..2047
            int o  = f4 >> 4;             // 0..127
            int kq = f4 & 15;             // 0..15 (float4 within 64-wide chunk)
            float4 w = *(const float4*)(Wrows + o * HH + kc * 64 + kq * 4);
            float* dst = sWt + (kq * 4) * HH + o;
            dst[0 * HH] = w.x;
            dst[1 * HH] = w.y;
            dst[2 * HH] = w.z;
            dst[3 * HH] = w.w;
        }
        __syncthreads();
        const float* inb = in + brow * 4 * 132 + kc * 64;
#pragma unroll
        for (int kk4 = 0; kk4 < 16; ++kk4) {
            float hv[4][4], wv[4][4];
#pragma unroll
            for (int i = 0; i < 4; ++i) {
                float4 h4 = *(const float4*)(inb + i * 132 + kk4 * 4);
                hv[i][0] = h4.x; hv[i][1] = h4.y; hv[i][2] = h4.z; hv[i][3] = h4.w;
            }
#pragma unroll
            for (int k = 0; k < 4; ++k) {
                float4 w4 = *(const float4*)(sWt + (kk4 * 4 + k) * HH + ocol * 4);
                wv[k][0] = w4.x; wv[k][1] = w4.y; wv[k][2] = w4.z; wv[k][3] = w4.w;
            }
#pragma unroll
            for (int i = 0; i < 4; ++i)
#pragma unroll
                for (int j = 0; j < 4; ++j)
#pragma unroll
                    for (int k = 0; k < 4; ++k)
                        acc[i][j] = fmaf(hv[i][k], wv[k][j], acc[i][j]);
        }
    }
}

__global__ __launch_bounds__(256, 2) void gru_kernel(
    const int* __restrict__ ids,
    const float* __restrict__ emb_a, const float* __restrict__ emb_c,
    const float* __restrict__ W_ih, const float* __restrict__ W_hh,
    const float* __restrict__ b_ih, const float* __restrict__ b_hh,
    float* __restrict__ ha, float* __restrict__ hc)
{
    __shared__ float sh[32][132];
    __shared__ float sx[32][132];
    __shared__ float sWt[64 * HH];

    const int tid = threadIdx.x;
    const int b0 = blockIdx.x * 32;
    const float* emb = blockIdx.y ? emb_c : emb_a;
    float* hout = blockIdx.y ? hc : ha;

    const int ocol = tid & 31;   // output col group: o = ocol*4 + j
    const int brow = tid >> 5;   // batch row group: b = brow*4 + i

    // h = 0
    for (int q = tid; q < 32 * 132; q += 256) (&sh[0][0])[q] = 0.f;

    // biases for this thread's 4 output columns, per gate
    float bir[4], bhr[4], biz[4], bhz[4], bin[4], bhn[4];
    {
        float4 v;
        v = *(const float4*)(b_ih + 0   + ocol * 4); bir[0]=v.x; bir[1]=v.y; bir[2]=v.z; bir[3]=v.w;
        v = *(const float4*)(b_hh + 0   + ocol * 4); bhr[0]=v.x; bhr[1]=v.y; bhr[2]=v.z; bhr[3]=v.w;
        v = *(const float4*)(b_ih + 128 + ocol * 4); biz[0]=v.x; biz[1]=v.y; biz[2]=v.z; biz[3]=v.w;
        v = *(const float4*)(b_hh + 128 + ocol * 4); bhz[0]=v.x; bhz[1]=v.y; bhz[2]=v.z; bhz[3]=v.w;
        v = *(const float4*)(b_ih + 256 + ocol * 4); bin[0]=v.x; bin[1]=v.y; bin[2]=v.z; bin[3]=v.w;
        v = *(const float4*)(b_hh + 256 + ocol * 4); bhn[0]=v.x; bhn[1]=v.y; bhn[2]=v.z; bhn[3]=v.w;
    }

    const int gb = tid >> 3;  // gather: batch row 0..31
    const int gp = tid & 7;   // gather: part 0..7

    for (int t = 0; t < TT; ++t) {
        // gather x[b][:] = emb[ids[b][t]][:]
        {
            int id = ids[(b0 + gb) * TT + t];
            const float4* er = (const float4*)(emb + (long long)id * HH);
            float4* xr = (float4*)(&sx[gb][0]);
#pragma unroll
            for (int q = 0; q < 4; ++q) xr[gp + 8 * q] = er[gp + 8 * q];
        }

        float r_[4][4], z_[4][4], fin[4][4], acc[4][4];
#pragma unroll 1
        for (int p = 0; p < 6; ++p) {
            // passes: 0:(x,Wih,r) 1:(h,Whh,r) 2:(x,Wih,z) 3:(h,Whh,z) 4:(x,Wih,n) 5:(h,Whh,n)
            if ((p & 1) == 0 || p == 5) {
#pragma unroll
                for (int i = 0; i < 4; ++i)
#pragma unroll
                    for (int j = 0; j < 4; ++j) acc[i][j] = 0.f;
            }
            const float* inp = (p & 1) ? &sh[0][0] : &sx[0][0];
            const float* Wp  = ((p & 1) ? W_hh : W_ih) + (long long)(p >> 1) * 128 * HH;
            gemm_pass(inp, Wp, acc, sWt, tid, ocol, brow);
            if (p == 1) {
#pragma unroll
                for (int i = 0; i < 4; ++i)
#pragma unroll
                    for (int j = 0; j < 4; ++j)
                        r_[i][j] = sigmoidf_(acc[i][j] + bir[j] + bhr[j]);
            } else if (p == 3) {
#pragma unroll
                for (int i = 0; i < 4; ++i)
#pragma unroll
                    for (int j = 0; j < 4; ++j)
                        z_[i][j] = sigmoidf_(acc[i][j] + biz[j] + bhz[j]);
            } else if (p == 4) {
#pragma unroll
                for (int i = 0; i < 4; ++i)
#pragma unroll
                    for (int j = 0; j < 4; ++j)
                        fin[i][j] = acc[i][j] + bin[j];
            }
        }
        // acc now holds raw h-side n-gate; read old h before overwrite
        float hold[4][4];
#pragma unroll
        for (int i = 0; i < 4; ++i) {
            float4 h4 = *(const float4*)(&sh[brow * 4 + i][ocol * 4]);
            hold[i][0] = h4.x; hold[i][1] = h4.y; hold[i][2] = h4.z; hold[i][3] = h4.w;
        }
        __syncthreads();
#pragma unroll
        for (int i = 0; i < 4; ++i) {
            float vals[4];
#pragma unroll
            for (int j = 0; j < 4; ++j) {
                float hn = acc[i][j] + bhn[j];
                float nn = tanhf_(fin[i][j] + r_[i][j] * hn);
                vals[j] = (1.f - z_[i][j]) * nn + z_[i][j] * hold[i][j];
            }
            float4 o4 = make_float4(vals[0], vals[1], vals[2], vals[3]);
            *(float4*)(&sh[brow * 4 + i][ocol * 4]) = o4;
            *(float4*)(hout + ((long long)(b0 + brow * 4 + i) * TT + t) * HH + ocol * 4) = o4;
        }
    }
}

__global__ __launch_bounds__(256, 2) void attn_cls_kernel(
    const float* __restrict__ ha, const float* __restrict__ hc,
    const float* __restrict__ W_cls, const float* __restrict__ b_cls,
    float* __restrict__ out)
{
    __shared__ float shaT[128 * 44];   // ha transposed [k][t], pad 44; reused for logits [40][104]
    __shared__ float shc[40 * HH];
    __shared__ float sm[40 * 40];      // Gram matrix, then weights in-place
    __shared__ float sout[40 * HH];
    __shared__ float sM[40], sDi[40], sM2[40], sDi2[40];
    float* slog = shaT;

    const int tid = threadIdx.x;
    const long long b = blockIdx.x;

    // P0: load ha (transposed) and hc
    const float4* hab = (const float4*)(ha + b * TT * HH);
    const float4* hcb = (const float4*)(hc + b * TT * HH);
#pragma unroll
    for (int q = 0; q < 5; ++q) {
        int f4 = tid + 256 * q;        // 0..1279
        int t = f4 >> 5, kq = f4 & 31;
        float4 v = hab[f4];
        shaT[(kq * 4 + 0) * 44 + t] = v.x;
        shaT[(kq * 4 + 1) * 44 + t] = v.y;
        shaT[(kq * 4 + 2) * 44 + t] = v.z;
        shaT[(kq * 4 + 3) * 44 + t] = v.w;
        ((float4*)shc)[f4] = hcb[f4];
    }
    __syncthreads();

    // P1: m[t][s] = ha[t]·ha[s]; symmetric, 4x4 tiles with ti<=si (55 tiles)
    if (tid < 55) {
        int ti = 0, rem = tid;
        while (rem >= 10 - ti) { rem -= 10 - ti; ++ti; }
        int si = ti + rem;
        float acc[4][4] = {};
        for (int k = 0; k < HH; ++k) {
            const float* row = shaT + k * 44;
            float4 av = *(const float4*)(row + ti * 4);
            float4 bv = *(const float4*)(row + si * 4);
            float a[4] = {av.x, av.y, av.z, av.w};
            float c[4] = {bv.x, bv.y, bv.z, bv.w};
#pragma unroll
            for (int i = 0; i < 4; ++i)
#pragma unroll
                for (int j = 0; j < 4; ++j)
                    acc[i][j] = fmaf(a[i], c[j], acc[i][j]);
        }
#pragma unroll
        for (int i = 0; i < 4; ++i)
#pragma unroll
            for (int j = 0; j < 4; ++j) {
                sm[(ti * 4 + i) * 40 + si * 4 + j] = acc[i][j];
                sm[(si * 4 + j) * 40 + ti * 4 + i] = acc[i][j];
            }
    }
    __syncthreads();

    // P2: per-row (== per-column, symmetric) max and exp-sum
    if (tid < 40) {
        const float* row = sm + tid * 40;
        float M = row[0];
        for (int s = 1; s < 40; ++s) M = fmaxf(M, row[s]);
        float D = 0.f;
        for (int s = 0; s < 40; ++s) D += __expf(row[s] - M);
        sM[tid] = M; sDi[tid] = 1.f / D;
    }
    __syncthreads();

    // P3: w[s][t] = exp(m[s][t]-M[t]) / D[t]  (column-normalized), in place
    for (int idx = tid; idx < 1600; idx += 256) {
        int c = idx % 40;
        sm[idx] = __expf(sm[idx] - sM[c]) * sDi[c];
    }
    __syncthreads();

    // P4: out[s][h] = sum_t w[s][t] * hc[t][h]
#pragma unroll
    for (int q = 0; q < 5; ++q) {
        int task = tid + 256 * q;      // 0..1279
        int s = task >> 5, hg = task & 31;
        float4 acc = {0.f, 0.f, 0.f, 0.f};
        const float* wrow = sm + s * 40;
        for (int t2 = 0; t2 < 40; ++t2) {
            float w = wrow[t2];
            float4 hv = *(const float4*)(shc + t2 * HH + hg * 4);
            acc.x = fmaf(w, hv.x, acc.x);
            acc.y = fmaf(w, hv.y, acc.y);
            acc.z = fmaf(w, hv.z, acc.z);
            acc.w = fmaf(w, hv.w, acc.w);
        }
        *(float4*)(sout + s * HH + hg * 4) = acc;
    }
    __syncthreads();

    // P5: logits[s][c] = out[s]·W_cls[c] + b_cls[c]; thread = (c, half of s range)
    if (tid < 2 * CC) {
        int c = tid >> 1, half = tid & 1;
        float acc[20] = {};
        const float* wr = W_cls + c * HH;
#pragma unroll 1
        for (int kc = 0; kc < 8; ++kc) {
            float4 w0 = *(const float4*)(wr + kc * 16 + 0);
            float4 w1 = *(const float4*)(wr + kc * 16 + 4);
            float4 w2 = *(const float4*)(wr + kc * 16 + 8);
            float4 w3 = *(const float4*)(wr + kc * 16 + 12);
#pragma unroll
            for (int si = 0; si < 20; ++si) {
                const float* orow = sout + (half * 20 + si) * HH + kc * 16;
                float4 o0 = *(const float4*)(orow + 0);
                float4 o1 = *(const float4*)(orow + 4);
                float4 o2 = *(const float4*)(orow + 8);
                float4 o3 = *(const float4*)(orow + 12);
                float s0 = w0.x * o0.x + w0.y * o0.y + w0.z * o0.z + w0.w * o0.w;
                float s1 = w1.x * o1.x + w1.y * o1.y + w1.z * o1.z + w1.w * o1.w;
                float s2 = w2.x * o2.x + w2.y * o2.y + w2.z * o2.z + w2.w * o2.w;
                float s3 = w3.x * o3.x + w3.y * o3.y + w3.z * o3.z + w3.w * o3.w;
                acc[si] += (s0 + s1) + (s2 + s3);
            }
        }
        float bc = b_cls[c];
#pragma unroll
        for (int si = 0; si < 20; ++si)
            slog[(half * 20 + si) * 104 + c] = acc[si] + bc;
    }
    __syncthreads();

    // P6: softmax stats over classes per s
    if (tid < 40) {
        const float* row = slog + tid * 104;
        float M = row[0];
        for (int c2 = 1; c2 < CC; ++c2) M = fmaxf(M, row[c2]);
        float D = 0.f;
        for (int c2 = 0; c2 < CC; ++c2) D += __expf(row[c2] - M);
        sM2[tid] = M; sDi2[tid] = 1.f / D;
    }
    __syncthreads();

    // P7: write softmax probs
    float* ob = out + b * TT * CC;
    for (int idx = tid; idx < TT * CC; idx += 256) {
        int s = idx / CC;
        int c = idx - s * CC;
        ob[idx] = __expf(slog[s * 104 + c] - sM2[s]) * sDi2[s];
    }
}

extern "C" void kernel_launch(void* const* d_in, const int* in_sizes, int n_in,
                              void* d_out, int out_size, void* d_ws, size_t ws_size,
                              hipStream_t stream) {
    const int*   ids   = (const int*)d_in[0];
    const float* emb_c = (const float*)d_in[1];
    const float* emb_a = (const float*)d_in[2];
    const float* W_ih  = (const float*)d_in[3];
    const float* W_hh  = (const float*)d_in[4];
    const float* b_ih  = (const float*)d_in[5];
    const float* b_hh  = (const float*)d_in[6];
    const float* W_cls = (const float*)d_in[7];
    const float* b_cls = (const float*)d_in[8];
    float* out = (float*)d_out;

    float* ha = (float*)d_ws;                       // [B][T][H] fp32
    float* hc = ha + (size_t)BB * TT * HH;          // [B][T][H] fp32

    gru_kernel<<<dim3(BB / 32, 2), 256, 0, stream>>>(ids, emb_a, emb_c, W_ih, W_hh,
                                                     b_ih, b_hh, ha, hc);
    attn_cls_kernel<<<BB, 256, 0, stream>>>(ha, hc, W_cls, b_cls, out);
}

// Round 2
// 1388.771 us; speedup vs baseline: 2.8698x; 2.8698x over previous
//
#include <hip/hip_runtime.h>
#include <hip/hip_bf16.h>

#define BB 8192
#define TT 40
#define HH 128
#define CC 102
#define VV 4450

typedef __attribute__((ext_vector_type(8))) short short8;
typedef __attribute__((ext_vector_type(4))) float f4;

__device__ __forceinline__ float sigmoidf_(float x) { return 1.f / (1.f + __expf(-x)); }
__device__ __forceinline__ float tanhf_(float x) { float e = __expf(2.f * x); return 1.f - 2.f / (e + 1.f); }

// ---------- prep 1: split W_hh into bf16 hi/lo ----------
__global__ __launch_bounds__(256) void prep_split(const float* __restrict__ W,
                                                  __hip_bfloat16* __restrict__ hi,
                                                  __hip_bfloat16* __restrict__ lo) {
    int i = blockIdx.x * 256 + threadIdx.x;
    if (i < 384 * HH) {
        float x = W[i];
        __hip_bfloat16 h = __float2bfloat16(x);
        float rem = x - __bfloat162float(h);
        hi[i] = h;
        lo[i] = __float2bfloat16(rem);
    }
}

// ---------- prep 2: G[src][v][c] = emb[v] @ W_ih^T + biases ----------
// c in [0,128): r-gate,   + b_ih + b_hh
// c in [128,256): z-gate, + b_ih + b_hh
// c in [256,384): i_n,    + b_ih only (b_hh_n applied in GRU epilogue)
__global__ __launch_bounds__(256) void prep_G(
    const float* __restrict__ emb_a, const float* __restrict__ emb_c,
    const float* __restrict__ W_ih, const float* __restrict__ b_ih,
    const float* __restrict__ b_hh, float* __restrict__ G)
{
    __shared__ float se[32][132];
    const int src = blockIdx.y;
    const float* emb = src ? emb_c : emb_a;
    const int v0 = blockIdx.x * 32;

    for (int q = threadIdx.x; q < 1024; q += 256) {   // 32 rows x 32 float4
        int r = q >> 5, kq = q & 31;
        int v = v0 + r;
        float4 e = make_float4(0.f, 0.f, 0.f, 0.f);
        if (v < VV) e = ((const float4*)(emb + (size_t)v * HH))[kq];
        *(float4*)&se[r][kq * 4] = e;
    }
    __syncthreads();

    int row = threadIdx.x >> 3, colg = threadIdx.x & 7;
    int v = v0 + row;
    if (v >= VV) return;
    float* gout = G + ((size_t)src * VV + v) * 384;
    const float4* er = (const float4*)&se[row][0];
#pragma unroll 1
    for (int c = colg * 48; c < colg * 48 + 48; ++c) {
        const float4* wr = (const float4*)(W_ih + (size_t)c * HH);
        float s = 0.f;
#pragma unroll
        for (int k = 0; k < 32; ++k) {
            float4 w = wr[k], e = er[k];
            s += w.x * e.x + w.y * e.y + w.z * e.z + w.w * e.w;
        }
        float bias = b_ih[c] + (c < 256 ? b_hh[c] : 0.f);
        gout[c] = s + bias;
    }
}

// ---------- main GRU: h-side recurrence via bf16 hi/lo split MFMA ----------
// 256 blocks = 2 sources x 128 batch-tiles of M=64. 512 threads = 8 waves.
// Wave w handles N-cols [w*16, w*16+16) of each of {r, z, h_n}.
// W_hh fragments register-resident (hi+lo). h state in LDS (bf16 hi/lo,
// XOR-swizzled, double-buffered). x-side comes from G gather (L3).
__global__ __launch_bounds__(512, 2) void gru_mfma(
    const int* __restrict__ ids, const float* __restrict__ G,
    const __hip_bfloat16* __restrict__ Whi, const __hip_bfloat16* __restrict__ Wlo,
    const float* __restrict__ b_hh, float* __restrict__ ha, float* __restrict__ hc)
{
    __shared__ uint4 sh[2][2][64][16];   // [buf][hi/lo][row m][swizzled 16B slot]
    __shared__ int sids[64 * TT];

    const int tid = threadIdx.x;
    const int src = blockIdx.y;
    const int b0 = blockIdx.x * 64;
    const float* Gs = G + (size_t)src * VV * 384;
    float* hout = src ? hc : ha;

    const int lane = tid & 63;
    const int w = tid >> 6;
    const int nc0 = w * 16;
    const int mcol = lane & 15;   // A-frag m / B-frag n / C-frag col
    const int quad = lane >> 4;

    // stage ids (coalesced; rows b0..b0+63 are contiguous)
    for (int idx = tid; idx < 64 * TT; idx += 512)
        sids[idx] = ids[b0 * TT + idx];

    // zero h buffer 0 (bf16 +0.0 = 0x0000)
    {
        uint4 z; z.x = z.y = z.z = z.w = 0u;
        uint4* p = &sh[0][0][0][0];
        for (int idx = tid; idx < 2 * 64 * 16; idx += 512) p[idx] = z;
    }

    // register-resident W_hh B-fragments: lane holds W[g*128+nc0+mcol][kk*32+quad*8 ..+7]
    short8 bh[3][4], bl[3][4];
#pragma unroll
    for (int g = 0; g < 3; ++g)
#pragma unroll
        for (int kk = 0; kk < 4; ++kk) {
            int row = g * 128 + nc0 + mcol;
            uint4 vh = *((const uint4*)Whi + row * 16 + kk * 4 + quad);
            uint4 vl = *((const uint4*)Wlo + row * 16 + kk * 4 + quad);
            bh[g][kk] = *(short8*)&vh;
            bl[g][kk] = *(short8*)&vl;
        }

    const float bhn = b_hh[256 + nc0 + mcol];

    f4 hreg[4];
#pragma unroll
    for (int mt = 0; mt < 4; ++mt) hreg[mt] = (f4){0.f, 0.f, 0.f, 0.f};

    __syncthreads();

    int buf = 0;
#pragma unroll 1
    for (int t = 0; t < TT; ++t) {
        f4 acc[3][4];
#pragma unroll
        for (int g = 0; g < 3; ++g)
#pragma unroll
            for (int mt = 0; mt < 4; ++mt) acc[g][mt] = (f4){0.f, 0.f, 0.f, 0.f};

        // --- MFMA over K=128, M-tiles 0..1 ---
#pragma unroll
        for (int mt = 0; mt < 2; ++mt)
#pragma unroll
            for (int kk = 0; kk < 4; ++kk) {
                int m = mt * 16 + mcol;
                int phys = (kk * 4 + quad) ^ mcol;
                uint4 avh = sh[buf][0][m][phys];
                uint4 avl = sh[buf][1][m][phys];
                short8 ah = *(short8*)&avh, al = *(short8*)&avl;
#pragma unroll
                for (int g = 0; g < 3; ++g) {
                    acc[g][mt] = __builtin_amdgcn_mfma_f32_16x16x32_bf16(ah, bh[g][kk], acc[g][mt], 0, 0, 0);
                    acc[g][mt] = __builtin_amdgcn_mfma_f32_16x16x32_bf16(ah, bl[g][kk], acc[g][mt], 0, 0, 0);
                    acc[g][mt] = __builtin_amdgcn_mfma_f32_16x16x32_bf16(al, bh[g][kk], acc[g][mt], 0, 0, 0);
                }
            }

        // --- issue x-side (G table) gathers; latency hidden by M-tiles 2..3 ---
        float gi[3][4][4];
#pragma unroll
        for (int mt = 0; mt < 4; ++mt)
#pragma unroll
            for (int reg = 0; reg < 4; ++reg) {
                int m = mt * 16 + quad * 4 + reg;
                int id = sids[m * TT + t];
                const float* gp = Gs + (size_t)id * 384 + nc0 + mcol;
                gi[0][mt][reg] = gp[0];
                gi[1][mt][reg] = gp[128];
                gi[2][mt][reg] = gp[256];
            }

        // --- MFMA M-tiles 2..3 ---
#pragma unroll
        for (int mt = 2; mt < 4; ++mt)
#pragma unroll
            for (int kk = 0; kk < 4; ++kk) {
                int m = mt * 16 + mcol;
                int phys = (kk * 4 + quad) ^ mcol;
                uint4 avh = sh[buf][0][m][phys];
                uint4 avl = sh[buf][1][m][phys];
                short8 ah = *(short8*)&avh, al = *(short8*)&avl;
#pragma unroll
                for (int g = 0; g < 3; ++g) {
                    acc[g][mt] = __builtin_amdgcn_mfma_f32_16x16x32_bf16(ah, bh[g][kk], acc[g][mt], 0, 0, 0);
                    acc[g][mt] = __builtin_amdgcn_mfma_f32_16x16x32_bf16(ah, bl[g][kk], acc[g][mt], 0, 0, 0);
                    acc[g][mt] = __builtin_amdgcn_mfma_f32_16x16x32_bf16(al, bh[g][kk], acc[g][mt], 0, 0, 0);
                }
            }

        // --- epilogue: gates, h update, stores ---
        const int nbuf = buf ^ 1;
        const int j = nc0 + mcol;
        const int s_slot = j >> 3;
        const int jb = j & 7;
#pragma unroll
        for (int mt = 0; mt < 4; ++mt) {
#pragma unroll
            for (int reg = 0; reg < 4; ++reg) {
                float rr = sigmoidf_(acc[0][mt][reg] + gi[0][mt][reg]);
                float zz = sigmoidf_(acc[1][mt][reg] + gi[1][mt][reg]);
                float nn = tanhf_(gi[2][mt][reg] + rr * (acc[2][mt][reg] + bhn));
                float hv = (1.f - zz) * nn + zz * hreg[mt][reg];
                hreg[mt][reg] = hv;

                int m = mt * 16 + quad * 4 + reg;
                hout[((size_t)(b0 + m) * TT + t) * HH + j] = hv;

                __hip_bfloat16 hb = __float2bfloat16(hv);
                float rem = hv - __bfloat162float(hb);
                __hip_bfloat16 lb = __float2bfloat16(rem);
                int phys = s_slot ^ (m & 15);
                ((__hip_bfloat16*)&sh[nbuf][0][m][phys])[jb] = hb;
                ((__hip_bfloat16*)&sh[nbuf][1][m][phys])[jb] = lb;
            }
        }
        __syncthreads();
        buf ^= 1;
    }
}

// ---------- attention + classifier (unchanged from round 1) ----------
__global__ __launch_bounds__(256, 2) void attn_cls_kernel(
    const float* __restrict__ ha, const float* __restrict__ hc,
    const float* __restrict__ W_cls, const float* __restrict__ b_cls,
    float* __restrict__ out)
{
    __shared__ float shaT[128 * 44];
    __shared__ float shc[40 * HH];
    __shared__ float sm[40 * 40];
    __shared__ float sout[40 * HH];
    __shared__ float sM[40], sDi[40], sM2[40], sDi2[40];
    float* slog = shaT;

    const int tid = threadIdx.x;
    const long long b = blockIdx.x;

    const float4* hab = (const float4*)(ha + b * TT * HH);
    const float4* hcb = (const float4*)(hc + b * TT * HH);
#pragma unroll
    for (int q = 0; q < 5; ++q) {
        int f4i = tid + 256 * q;
        int t = f4i >> 5, kq = f4i & 31;
        float4 v = hab[f4i];
        shaT[(kq * 4 + 0) * 44 + t] = v.x;
        shaT[(kq * 4 + 1) * 44 + t] = v.y;
        shaT[(kq * 4 + 2) * 44 + t] = v.z;
        shaT[(kq * 4 + 3) * 44 + t] = v.w;
        ((float4*)shc)[f4i] = hcb[f4i];
    }
    __syncthreads();

    if (tid < 55) {
        int ti = 0, rem = tid;
        while (rem >= 10 - ti) { rem -= 10 - ti; ++ti; }
        int si = ti + rem;
        float acc[4][4] = {};
        for (int k = 0; k < HH; ++k) {
            const float* row = shaT + k * 44;
            float4 av = *(const float4*)(row + ti * 4);
            float4 bv = *(const float4*)(row + si * 4);
            float a[4] = {av.x, av.y, av.z, av.w};
            float c[4] = {bv.x, bv.y, bv.z, bv.w};
#pragma unroll
            for (int i = 0; i < 4; ++i)
#pragma unroll
                for (int jj = 0; jj < 4; ++jj)
                    acc[i][jj] = fmaf(a[i], c[jj], acc[i][jj]);
        }
#pragma unroll
        for (int i = 0; i < 4; ++i)
#pragma unroll
            for (int jj = 0; jj < 4; ++jj) {
                sm[(ti * 4 + i) * 40 + si * 4 + jj] = acc[i][jj];
                sm[(si * 4 + jj) * 40 + ti * 4 + i] = acc[i][jj];
            }
    }
    __syncthreads();

    if (tid < 40) {
        const float* row = sm + tid * 40;
        float M = row[0];
        for (int s = 1; s < 40; ++s) M = fmaxf(M, row[s]);
        float D = 0.f;
        for (int s = 0; s < 40; ++s) D += __expf(row[s] - M);
        sM[tid] = M; sDi[tid] = 1.f / D;
    }
    __syncthreads();

    for (int idx = tid; idx < 1600; idx += 256) {
        int c = idx % 40;
        sm[idx] = __expf(sm[idx] - sM[c]) * sDi[c];
    }
    __syncthreads();

#pragma unroll
    for (int q = 0; q < 5; ++q) {
        int task = tid + 256 * q;
        int s = task >> 5, hg = task & 31;
        float4 acc = {0.f, 0.f, 0.f, 0.f};
        const float* wrow = sm + s * 40;
        for (int t2 = 0; t2 < 40; ++t2) {
            float wv = wrow[t2];
            float4 hv = *(const float4*)(shc + t2 * HH + hg * 4);
            acc.x = fmaf(wv, hv.x, acc.x);
            acc.y = fmaf(wv, hv.y, acc.y);
            acc.z = fmaf(wv, hv.z, acc.z);
            acc.w = fmaf(wv, hv.w, acc.w);
        }
        *(float4*)(sout + s * HH + hg * 4) = acc;
    }
    __syncthreads();

    if (tid < 2 * CC) {
        int c = tid >> 1, half = tid & 1;
        float acc[20] = {};
        const float* wr = W_cls + c * HH;
#pragma unroll 1
        for (int kc = 0; kc < 8; ++kc) {
            float4 w0 = *(const float4*)(wr + kc * 16 + 0);
            float4 w1 = *(const float4*)(wr + kc * 16 + 4);
            float4 w2 = *(const float4*)(wr + kc * 16 + 8);
            float4 w3 = *(const float4*)(wr + kc * 16 + 12);
#pragma unroll
            for (int si = 0; si < 20; ++si) {
                const float* orow = sout + (half * 20 + si) * HH + kc * 16;
                float4 o0 = *(const float4*)(orow + 0);
                float4 o1 = *(const float4*)(orow + 4);
                float4 o2 = *(const float4*)(orow + 8);
                float4 o3 = *(const float4*)(orow + 12);
                float s0 = w0.x * o0.x + w0.y * o0.y + w0.z * o0.z + w0.w * o0.w;
                float s1 = w1.x * o1.x + w1.y * o1.y + w1.z * o1.z + w1.w * o1.w;
                float s2 = w2.x * o2.x + w2.y * o2.y + w2.z * o2.z + w2.w * o2.w;
                float s3 = w3.x * o3.x + w3.y * o3.y + w3.z * o3.z + w3.w * o3.w;
                acc[si] += (s0 + s1) + (s2 + s3);
            }
        }
        float bc = b_cls[c];
#pragma unroll
        for (int si = 0; si < 20; ++si)
            slog[(half * 20 + si) * 104 + c] = acc[si] + bc;
    }
    __syncthreads();

    if (tid < 40) {
        const float* row = slog + tid * 104;
        float M = row[0];
        for (int c2 = 1; c2 < CC; ++c2) M = fmaxf(M, row[c2]);
        float D = 0.f;
        for (int c2 = 0; c2 < CC; ++c2) D += __expf(row[c2] - M);
        sM2[tid] = M; sDi2[tid] = 1.f / D;
    }
    __syncthreads();

    float* ob = out + b * TT * CC;
    for (int idx = tid; idx < TT * CC; idx += 256) {
        int s = idx / CC;
        int c = idx - s * CC;
        ob[idx] = __expf(slog[s * 104 + c] - sM2[s]) * sDi2[s];
    }
}

extern "C" void kernel_launch(void* const* d_in, const int* in_sizes, int n_in,
                              void* d_out, int out_size, void* d_ws, size_t ws_size,
                              hipStream_t stream) {
    const int*   ids   = (const int*)d_in[0];
    const float* emb_c = (const float*)d_in[1];
    const float* emb_a = (const float*)d_in[2];
    const float* W_ih  = (const float*)d_in[3];
    const float* W_hh  = (const float*)d_in[4];
    const float* b_ih  = (const float*)d_in[5];
    const float* b_hh  = (const float*)d_in[6];
    const float* W_cls = (const float*)d_in[7];
    const float* b_cls = (const float*)d_in[8];
    float* out = (float*)d_out;

    float* ha = (float*)d_ws;                               // [B][T][H] fp32
    float* hc = ha + (size_t)BB * TT * HH;                  // [B][T][H] fp32
    float* G  = hc + (size_t)BB * TT * HH;                  // [2][V][384] fp32
    __hip_bfloat16* Whi = (__hip_bfloat16*)(G + (size_t)2 * VV * 384);
    __hip_bfloat16* Wlo = Whi + 384 * HH;

    prep_split<<<(384 * HH + 255) / 256, 256, 0, stream>>>(W_hh, Whi, Wlo);
    prep_G<<<dim3((VV + 31) / 32, 2), 256, 0, stream>>>(emb_a, emb_c, W_ih, b_ih, b_hh, G);
    gru_mfma<<<dim3(BB / 64, 2), 512, 0, stream>>>(ids, G, Whi, Wlo, b_hh, ha, hc);
    attn_cls_kernel<<<BB, 256, 0, stream>>>(ha, hc, W_cls, b_cls, out);
}

// Round 3
// 994.684 us; speedup vs baseline: 4.0067x; 1.3962x over previous
//
#include <hip/hip_runtime.h>
#include <hip/hip_bf16.h>

#define BB 8192
#define TT 40
#define HH 128
#define CC 102
#define VV 4450

typedef __attribute__((ext_vector_type(8))) short short8;
typedef __attribute__((ext_vector_type(4))) float f4;

__device__ __forceinline__ float sigmoidf_(float x) { return 1.f / (1.f + __expf(-x)); }
__device__ __forceinline__ float tanhf_(float x) { float e = __expf(2.f * x); return 1.f - 2.f / (e + 1.f); }

__device__ __forceinline__ unsigned short f2bf(float x) {
    union { float f; unsigned u; } v; v.f = x;
    unsigned r = v.u + 0x7FFFu + ((v.u >> 16) & 1u);
    return (unsigned short)(r >> 16);
}
__device__ __forceinline__ float bf2f(unsigned short h) {
    union { float f; unsigned u; } v; v.u = ((unsigned)h) << 16; return v.f;
}
__device__ __forceinline__ short8 u4s8(uint4 v) { return *(short8*)&v; }

#define MFMA16(acc, a, b) acc = __builtin_amdgcn_mfma_f32_16x16x32_bf16(a, b, acc, 0, 0, 0)

// ---------- prep 1: split W_hh into bf16 hi/lo ----------
__global__ __launch_bounds__(256) void prep_split(const float* __restrict__ W,
                                                  __hip_bfloat16* __restrict__ hi,
                                                  __hip_bfloat16* __restrict__ lo) {
    int i = blockIdx.x * 256 + threadIdx.x;
    if (i < 384 * HH) {
        float x = W[i];
        unsigned short h = f2bf(x);
        ((unsigned short*)hi)[i] = h;
        ((unsigned short*)lo)[i] = f2bf(x - bf2f(h));
    }
}

// ---------- prep 1b: split W_cls into bf16 hi/lo, padded to 112 rows ----------
__global__ __launch_bounds__(256) void prep_wcls(const float* __restrict__ W,
                                                 unsigned short* __restrict__ hi,
                                                 unsigned short* __restrict__ lo) {
    int i = blockIdx.x * 256 + threadIdx.x;
    if (i < 112 * HH) {
        int r = i >> 7;
        float x = (r < CC) ? W[i] : 0.f;
        unsigned short h = f2bf(x);
        hi[i] = h;
        lo[i] = f2bf(x - bf2f(h));
    }
}

// ---------- prep 2: G[src][v][c] = emb[v] @ W_ih^T + biases ----------
__global__ __launch_bounds__(256) void prep_G(
    const float* __restrict__ emb_a, const float* __restrict__ emb_c,
    const float* __restrict__ W_ih, const float* __restrict__ b_ih,
    const float* __restrict__ b_hh, float* __restrict__ G)
{
    __shared__ float se[32][132];
    const int src = blockIdx.y;
    const float* emb = src ? emb_c : emb_a;
    const int v0 = blockIdx.x * 32;

    for (int q = threadIdx.x; q < 1024; q += 256) {
        int r = q >> 5, kq = q & 31;
        int v = v0 + r;
        float4 e = make_float4(0.f, 0.f, 0.f, 0.f);
        if (v < VV) e = ((const float4*)(emb + (size_t)v * HH))[kq];
        *(float4*)&se[r][kq * 4] = e;
    }
    __syncthreads();

    int row = threadIdx.x >> 3, colg = threadIdx.x & 7;
    int v = v0 + row;
    if (v >= VV) return;
    float* gout = G + ((size_t)src * VV + v) * 384;
    const float4* er = (const float4*)&se[row][0];
#pragma unroll 1
    for (int c = colg * 48; c < colg * 48 + 48; ++c) {
        const float4* wr = (const float4*)(W_ih + (size_t)c * HH);
        float s = 0.f;
#pragma unroll
        for (int k = 0; k < 32; ++k) {
            float4 w = wr[k], e = er[k];
            s += w.x * e.x + w.y * e.y + w.z * e.z + w.w * e.w;
        }
        float bias = b_ih[c] + (c < 256 ? b_hh[c] : 0.f);
        gout[c] = s + bias;
    }
}

// ---------- main GRU: M=32/block to avoid spills; G-gather prefetched ----------
__global__ __launch_bounds__(512, 2) void gru_mfma(
    const int* __restrict__ ids, const float* __restrict__ G,
    const __hip_bfloat16* __restrict__ Whi, const __hip_bfloat16* __restrict__ Wlo,
    const float* __restrict__ b_hh, float* __restrict__ ha, float* __restrict__ hc)
{
    __shared__ uint4 sh[2][2][32][16];
    __shared__ int sids[32 * TT];

    const int tid = threadIdx.x;
    const int src = blockIdx.y;
    const int b0 = blockIdx.x * 32;
    const float* Gs = G + (size_t)src * VV * 384;
    float* hout = src ? hc : ha;

    const int lane = tid & 63;
    const int w = tid >> 6;
    const int nc0 = w * 16;
    const int mcol = lane & 15;
    const int quad = lane >> 4;

    for (int idx = tid; idx < 32 * TT; idx += 512)
        sids[idx] = ids[b0 * TT + idx];

    {
        uint4 z; z.x = z.y = z.z = z.w = 0u;
        uint4* p = &sh[0][0][0][0];
        for (int idx = tid; idx < 2 * 32 * 16; idx += 512) p[idx] = z;
    }

    short8 bh[3][4], bl[3][4];
#pragma unroll
    for (int g = 0; g < 3; ++g)
#pragma unroll
        for (int kk = 0; kk < 4; ++kk) {
            int row = g * 128 + nc0 + mcol;
            uint4 vh = *((const uint4*)Whi + row * 16 + kk * 4 + quad);
            uint4 vl = *((const uint4*)Wlo + row * 16 + kk * 4 + quad);
            bh[g][kk] = u4s8(vh);
            bl[g][kk] = u4s8(vl);
        }

    const float bhn = b_hh[256 + nc0 + mcol];
    const float* gbase = Gs + nc0 + mcol;

    f4 hreg[2];
    hreg[0] = (f4){0.f, 0.f, 0.f, 0.f};
    hreg[1] = (f4){0.f, 0.f, 0.f, 0.f};

    __syncthreads();

    // prefetch x-side for t=0
    float gc[3][2][4];
#pragma unroll
    for (int mt = 0; mt < 2; ++mt)
#pragma unroll
        for (int reg = 0; reg < 4; ++reg) {
            int m = mt * 16 + quad * 4 + reg;
            int id = sids[m * TT + 0];
            const float* gp = gbase + (size_t)id * 384;
            gc[0][mt][reg] = gp[0];
            gc[1][mt][reg] = gp[128];
            gc[2][mt][reg] = gp[256];
        }

    int buf = 0;
#pragma unroll 1
    for (int t = 0; t < TT; ++t) {
        f4 acc[3][2];
#pragma unroll
        for (int g = 0; g < 3; ++g)
#pragma unroll
            for (int mt = 0; mt < 2; ++mt) acc[g][mt] = (f4){0.f, 0.f, 0.f, 0.f};

#pragma unroll
        for (int mt = 0; mt < 2; ++mt)
#pragma unroll
            for (int kk = 0; kk < 4; ++kk) {
                int m = mt * 16 + mcol;
                int phys = (kk * 4 + quad) ^ mcol;
                uint4 avh = sh[buf][0][m][phys];
                uint4 avl = sh[buf][1][m][phys];
                short8 ah = u4s8(avh), al = u4s8(avl);
#pragma unroll
                for (int g = 0; g < 3; ++g) {
                    MFMA16(acc[g][mt], ah, bh[g][kk]);
                    MFMA16(acc[g][mt], ah, bl[g][kk]);
                    MFMA16(acc[g][mt], al, bh[g][kk]);
                }
            }

        // epilogue
        const int nbuf = buf ^ 1;
        const int j = nc0 + mcol;
        const int s_slot = j >> 3;
        const int jb = j & 7;
#pragma unroll
        for (int mt = 0; mt < 2; ++mt) {
#pragma unroll
            for (int reg = 0; reg < 4; ++reg) {
                float rr = sigmoidf_(acc[0][mt][reg] + gc[0][mt][reg]);
                float zz = sigmoidf_(acc[1][mt][reg] + gc[1][mt][reg]);
                float nn = tanhf_(gc[2][mt][reg] + rr * (acc[2][mt][reg] + bhn));
                float hv = (1.f - zz) * nn + zz * hreg[mt][reg];
                hreg[mt][reg] = hv;

                int m = mt * 16 + quad * 4 + reg;
                hout[((size_t)(b0 + m) * TT + t) * HH + j] = hv;

                unsigned short hb = f2bf(hv);
                unsigned short lb = f2bf(hv - bf2f(hb));
                int phys = s_slot ^ (m & 15);
                ((unsigned short*)&sh[nbuf][0][m][phys])[jb] = hb;
                ((unsigned short*)&sh[nbuf][1][m][phys])[jb] = lb;
            }
        }

        // prefetch x-side for t+1 (consumed next iteration; hidden by barrier+MFMA)
        if (t < TT - 1) {
#pragma unroll
            for (int mt = 0; mt < 2; ++mt)
#pragma unroll
                for (int reg = 0; reg < 4; ++reg) {
                    int m = mt * 16 + quad * 4 + reg;
                    int id = sids[m * TT + t + 1];
                    const float* gp = gbase + (size_t)id * 384;
                    gc[0][mt][reg] = gp[0];
                    gc[1][mt][reg] = gp[128];
                    gc[2][mt][reg] = gp[256];
                }
        }
        __syncthreads();
        buf ^= 1;
    }
}

// ---------- attention + classifier, MFMA version ----------
// LDS layout (bytes), manually aliased:
#define AT_SHA     0          // ha hi  [48 rows][16 uint4 chunks, phys=c^(row&15)]
#define AT_SHA_LO  12288      // ha lo                  (later: sout hi/lo)
#define AT_SHCT    24576      // hc^T hi [128 rows h][8 chunks (k=t,64), phys=c^(h&7)]
#define AT_SHCT_LO 40960      // hc^T lo
#define AT_SM      57344      // fp32 [48][49] Gram     (later: slog fp32 [48][113])
#define AT_SW      66752      // softmax-W hi [48 rows s][8 chunks (k=t,64), phys=c^(s&7)]
#define AT_SW_LO   72896      // softmax-W lo
#define AT_PARTM   79040      // fp32 [48][4]
#define AT_PARTD   79808      // fp32 [48][4]
#define AT_SMX     80576      // fp32 [48]
#define AT_SDI     80768      // fp32 [48]
#define AT_TOTAL   80960

__global__ __launch_bounds__(256, 2) void attn_cls_mfma(
    const float* __restrict__ ha, const float* __restrict__ hc,
    const unsigned short* __restrict__ WcH, const unsigned short* __restrict__ WcL,
    const float* __restrict__ b_cls, float* __restrict__ out)
{
    __shared__ __attribute__((aligned(16))) char smem[AT_TOTAL];
    const int tid = threadIdx.x;
    const int lane = tid & 63;
    const int w = tid >> 6;
    const int quad = lane >> 4;
    const int col = lane & 15;
    const size_t b = blockIdx.x;

    float* sm    = (float*)(smem + AT_SM);
    float* slog  = (float*)(smem + AT_SM);     // alias (SM+SW region, stride 113)
    float* partM = (float*)(smem + AT_PARTM);
    float* partD = (float*)(smem + AT_PARTD);
    float* sMX   = (float*)(smem + AT_SMX);
    float* sDI   = (float*)(smem + AT_SDI);

    // ---- register-resident W_cls B-fragments (issued first; L2 latency hidden) ----
    const int ntc0 = (w < 3) ? w : 3;
    const int ntc1 = (w < 3) ? w + 4 : 3;
    uint4 bw[2][4][2];
    float bcv[2];
    {
        int nts[2] = {ntc0, ntc1};
#pragma unroll
        for (int which = 0; which < 2; ++which) {
            int row = nts[which] * 16 + col;
#pragma unroll
            for (int kk = 0; kk < 4; ++kk) {
                bw[which][kk][0] = *((const uint4*)WcH + row * 16 + kk * 4 + quad);
                bw[which][kk][1] = *((const uint4*)WcL + row * 16 + kk * 4 + quad);
            }
            bcv[which] = (row < CC) ? b_cls[row] : 0.f;
        }
    }

    // ---- Phase A: load ha -> sha(hi/lo), hc -> shcT(hi/lo, transposed) ----
    {
        const float4* hab = (const float4*)(ha + b * TT * HH);
#pragma unroll
        for (int i = 0; i < 5; ++i) {
            int f4i = tid + 256 * i;
            int row = f4i >> 5, q = f4i & 31;
            float4 v = hab[f4i];
            unsigned short h0 = f2bf(v.x), h1 = f2bf(v.y), h2 = f2bf(v.z), h3 = f2bf(v.w);
            unsigned short l0 = f2bf(v.x - bf2f(h0)), l1 = f2bf(v.y - bf2f(h1));
            unsigned short l2 = f2bf(v.z - bf2f(h2)), l3 = f2bf(v.w - bf2f(h3));
            uint2 Hw, Lw;
            Hw.x = (unsigned)h0 | ((unsigned)h1 << 16); Hw.y = (unsigned)h2 | ((unsigned)h3 << 16);
            Lw.x = (unsigned)l0 | ((unsigned)l1 << 16); Lw.y = (unsigned)l2 | ((unsigned)l3 << 16);
            int phys = (q >> 1) ^ (row & 15);
            int off = row * 256 + phys * 16 + (q & 1) * 8;
            *(uint2*)(smem + AT_SHA + off) = Hw;
            *(uint2*)(smem + AT_SHA_LO + off) = Lw;
        }
        if (tid < 128) {  // zero sha rows 40..47
            int row = 40 + (tid >> 4), c = tid & 15;
            uint4 z; z.x = z.y = z.z = z.w = 0u;
            *(uint4*)(smem + AT_SHA + row * 256 + c * 16) = z;
            *(uint4*)(smem + AT_SHA_LO + row * 256 + c * 16) = z;
        }
        const float* hcb = hc + b * TT * HH;
        for (int task = tid; task < 640; task += 256) {   // (h, t-chunk of 8)
            int h = task & 127, c = task >> 7;
            unsigned short H8[8], L8[8];
#pragma unroll
            for (int jj = 0; jj < 8; ++jj) {
                float x = hcb[(c * 8 + jj) * HH + h];
                H8[jj] = f2bf(x);
                L8[jj] = f2bf(x - bf2f(H8[jj]));
            }
            uint4 Hq, Lq;
            Hq.x = (unsigned)H8[0] | ((unsigned)H8[1] << 16); Hq.y = (unsigned)H8[2] | ((unsigned)H8[3] << 16);
            Hq.z = (unsigned)H8[4] | ((unsigned)H8[5] << 16); Hq.w = (unsigned)H8[6] | ((unsigned)H8[7] << 16);
            Lq.x = (unsigned)L8[0] | ((unsigned)L8[1] << 16); Lq.y = (unsigned)L8[2] | ((unsigned)L8[3] << 16);
            Lq.z = (unsigned)L8[4] | ((unsigned)L8[5] << 16); Lq.w = (unsigned)L8[6] | ((unsigned)L8[7] << 16);
            int phys = c ^ (h & 7);
            *(uint4*)(smem + AT_SHCT + h * 128 + phys * 16) = Hq;
            *(uint4*)(smem + AT_SHCT_LO + h * 128 + phys * 16) = Lq;
        }
        for (int task = tid; task < 384; task += 256) {   // zero t-chunks 5..7
            int h = task & 127, c = 5 + (task >> 7);
            int phys = c ^ (h & 7);
            uint4 z; z.x = z.y = z.z = z.w = 0u;
            *(uint4*)(smem + AT_SHCT + h * 128 + phys * 16) = z;
            *(uint4*)(smem + AT_SHCT_LO + h * 128 + phys * 16) = z;
        }
    }
    __syncthreads();

    // ---- Phase B: Gram m[t][s] (waves 0..2, mt = w) ----
    if (w < 3) {
        const int mt = w;
        uint4 aH[4], aL[4];
#pragma unroll
        for (int kk = 0; kk < 4; ++kk) {
            int phys = (kk * 4 + quad) ^ col;
            int off = (mt * 16 + col) * 256 + phys * 16;
            aH[kk] = *(uint4*)(smem + AT_SHA + off);
            aL[kk] = *(uint4*)(smem + AT_SHA_LO + off);
        }
        f4 acc[3];
#pragma unroll
        for (int nt = 0; nt < 3; ++nt) acc[nt] = (f4){0.f, 0.f, 0.f, 0.f};
#pragma unroll
        for (int kk = 0; kk < 4; ++kk) {
            short8 ah = u4s8(aH[kk]), al = u4s8(aL[kk]);
#pragma unroll
            for (int nt = 0; nt < 3; ++nt) {
                int phys = (kk * 4 + quad) ^ col;
                int off = (nt * 16 + col) * 256 + phys * 16;
                short8 bH = u4s8(*(uint4*)(smem + AT_SHA + off));
                short8 bL = u4s8(*(uint4*)(smem + AT_SHA_LO + off));
                MFMA16(acc[nt], ah, bH);
                MFMA16(acc[nt], ah, bL);
                MFMA16(acc[nt], al, bH);
            }
        }
#pragma unroll
        for (int nt = 0; nt < 3; ++nt)
#pragma unroll
            for (int r = 0; r < 4; ++r)
                sm[(mt * 16 + quad * 4 + r) * 49 + nt * 16 + col] = acc[nt][r];
    }
    __syncthreads();

    // ---- Gram softmax stats: per row t over s<40 ----
    if (tid < 160) {
        int t = tid >> 2, p = tid & 3;
        const float* row = sm + t * 49 + p * 10;
        float M = row[0];
#pragma unroll
        for (int i = 1; i < 10; ++i) M = fmaxf(M, row[i]);
        float D = 0.f;
#pragma unroll
        for (int i = 0; i < 10; ++i) D += __expf(row[i] - M);
        partM[t * 4 + p] = M;
        partD[t * 4 + p] = D;
    }
    __syncthreads();
    if (tid < 40) {
        float M = partM[tid * 4];
        M = fmaxf(M, partM[tid * 4 + 1]); M = fmaxf(M, partM[tid * 4 + 2]); M = fmaxf(M, partM[tid * 4 + 3]);
        float D = 0.f;
#pragma unroll
        for (int p = 0; p < 4; ++p) D += partD[tid * 4 + p] * __expf(partM[tid * 4 + p] - M);
        sMX[tid] = M;
        sDI[tid] = 1.f / D;
    }
    __syncthreads();

    // ---- build sW: W[s][t] = exp(m[s][t]-M[t])*Di[t], bf16 hi/lo, k-major over t (pad 64) ----
    for (int task = tid; task < 384; task += 256) {
        int s = task >> 3, c = task & 7;
        uint4 Hq, Lq;
        if (c >= 5) {
            Hq.x = Hq.y = Hq.z = Hq.w = 0u; Lq = Hq;
        } else {
            const float* srow = sm + s * 49 + c * 8;
            unsigned short H8[8], L8[8];
#pragma unroll
            for (int jj = 0; jj < 8; ++jj) {
                int t = c * 8 + jj;
                float wv = __expf(srow[jj] - sMX[t]) * sDI[t];
                H8[jj] = f2bf(wv);
                L8[jj] = f2bf(wv - bf2f(H8[jj]));
            }
            Hq.x = (unsigned)H8[0] | ((unsigned)H8[1] << 16); Hq.y = (unsigned)H8[2] | ((unsigned)H8[3] << 16);
            Hq.z = (unsigned)H8[4] | ((unsigned)H8[5] << 16); Hq.w = (unsigned)H8[6] | ((unsigned)H8[7] << 16);
            Lq.x = (unsigned)L8[0] | ((unsigned)L8[1] << 16); Lq.y = (unsigned)L8[2] | ((unsigned)L8[3] << 16);
            Lq.z = (unsigned)L8[4] | ((unsigned)L8[5] << 16); Lq.w = (unsigned)L8[6] | ((unsigned)L8[7] << 16);
        }
        int phys = c ^ (s & 7);
        *(uint4*)(smem + AT_SW + s * 128 + phys * 16) = Hq;
        *(uint4*)(smem + AT_SW_LO + s * 128 + phys * 16) = Lq;
    }
    __syncthreads();

    // ---- P4: out[s][h] = sum_t W[s][t] hc[t][h]; wave w handles h-tiles {w, w+4} ----
    {
        uint4 aH[3][2], aL[3][2];
#pragma unroll
        for (int mt = 0; mt < 3; ++mt)
#pragma unroll
            for (int kk = 0; kk < 2; ++kk) {
                int s = mt * 16 + col;
                int phys = (kk * 4 + quad) ^ (s & 7);
                aH[mt][kk] = *(uint4*)(smem + AT_SW + s * 128 + phys * 16);
                aL[mt][kk] = *(uint4*)(smem + AT_SW_LO + s * 128 + phys * 16);
            }
        f4 acc[3][2];
#pragma unroll
        for (int mt = 0; mt < 3; ++mt) { acc[mt][0] = (f4){0,0,0,0}; acc[mt][1] = (f4){0,0,0,0}; }
#pragma unroll
        for (int which = 0; which < 2; ++which) {
            int nt = w + which * 4;
            int hrow = nt * 16 + col;
#pragma unroll
            for (int kk = 0; kk < 2; ++kk) {
                int phys = (kk * 4 + quad) ^ (hrow & 7);
                short8 bH = u4s8(*(uint4*)(smem + AT_SHCT + hrow * 128 + phys * 16));
                short8 bL = u4s8(*(uint4*)(smem + AT_SHCT_LO + hrow * 128 + phys * 16));
#pragma unroll
                for (int mt = 0; mt < 3; ++mt) {
                    short8 ah = u4s8(aH[mt][kk]), al = u4s8(aL[mt][kk]);
                    MFMA16(acc[mt][which], ah, bH);
                    MFMA16(acc[mt][which], ah, bL);
                    MFMA16(acc[mt][which], al, bH);
                }
            }
        }
        __syncthreads();   // sha reads (Gram) done everywhere; sout will alias sha
#pragma unroll
        for (int which = 0; which < 2; ++which) {
            int h = (w + which * 4) * 16 + col;
            int chunk = h >> 3, hb7 = (h & 7) * 2;
#pragma unroll
            for (int mt = 0; mt < 3; ++mt)
#pragma unroll
                for (int r = 0; r < 4; ++r) {
                    float v = acc[mt][which][r];
                    int s = mt * 16 + quad * 4 + r;
                    unsigned short hbv = f2bf(v);
                    unsigned short lbv = f2bf(v - bf2f(hbv));
                    int phys = chunk ^ (s & 15);
                    *(unsigned short*)(smem + AT_SHA + s * 256 + phys * 16 + hb7) = hbv;
                    *(unsigned short*)(smem + AT_SHA_LO + s * 256 + phys * 16 + hb7) = lbv;
                }
        }
    }
    __syncthreads();

    // ---- classifier: logits[s][c] = out[s]·W_cls[c] + b_cls[c] ----
    {
        f4 acc[3][2];
#pragma unroll
        for (int mt = 0; mt < 3; ++mt) { acc[mt][0] = (f4){0,0,0,0}; acc[mt][1] = (f4){0,0,0,0}; }
#pragma unroll
        for (int kk = 0; kk < 4; ++kk)
#pragma unroll
            for (int mt = 0; mt < 3; ++mt) {
                int s = mt * 16 + col;
                int phys = (kk * 4 + quad) ^ (s & 15);
                short8 ah = u4s8(*(uint4*)(smem + AT_SHA + s * 256 + phys * 16));
                short8 al = u4s8(*(uint4*)(smem + AT_SHA_LO + s * 256 + phys * 16));
#pragma unroll
                for (int which = 0; which < 2; ++which) {
                    MFMA16(acc[mt][which], ah, u4s8(bw[which][kk][0]));
                    MFMA16(acc[mt][which], ah, u4s8(bw[which][kk][1]));
                    MFMA16(acc[mt][which], al, u4s8(bw[which][kk][0]));
                }
            }
        __syncthreads();   // sm/sW reads done; slog aliases that region
        int nts[2] = {ntc0, ntc1};
#pragma unroll
        for (int which = 0; which < 2; ++which) {
            int c = nts[which] * 16 + col;
#pragma unroll
            for (int mt = 0; mt < 3; ++mt)
#pragma unroll
                for (int r = 0; r < 4; ++r)
                    slog[(mt * 16 + quad * 4 + r) * 113 + c] = acc[mt][which][r] + bcv[which];
        }
    }
    __syncthreads();

    // ---- class softmax stats per s ----
    if (tid < 160) {
        int s = tid >> 2, p = tid & 3;
        int c0 = p * 26;
        int c1 = (c0 + 26 < CC) ? c0 + 26 : CC;
        const float* row = slog + s * 113;
        float M = row[c0];
        for (int c = c0 + 1; c < c1; ++c) M = fmaxf(M, row[c]);
        float D = 0.f;
        for (int c = c0; c < c1; ++c) D += __expf(row[c] - M);
        partM[s * 4 + p] = M;
        partD[s * 4 + p] = D;
    }
    __syncthreads();
    if (tid < 40) {
        float M = partM[tid * 4];
        M = fmaxf(M, partM[tid * 4 + 1]); M = fmaxf(M, partM[tid * 4 + 2]); M = fmaxf(M, partM[tid * 4 + 3]);
        float D = 0.f;
#pragma unroll
        for (int p = 0; p < 4; ++p) D += partD[tid * 4 + p] * __expf(partM[tid * 4 + p] - M);
        sMX[tid] = M;
        sDI[tid] = 1.f / D;
    }
    __syncthreads();

    // ---- write softmax probs ----
    {
        int c = tid & 127, s0 = tid >> 7;
        if (c < CC) {
            float* ob = out + b * TT * CC;
            for (int s = s0; s < TT; s += 2)
                ob[s * CC + c] = __expf(slog[s * 113 + c] - sMX[s]) * sDI[s];
        }
    }
}

extern "C" void kernel_launch(void* const* d_in, const int* in_sizes, int n_in,
                              void* d_out, int out_size, void* d_ws, size_t ws_size,
                              hipStream_t stream) {
    const int*   ids   = (const int*)d_in[0];
    const float* emb_c = (const float*)d_in[1];
    const float* emb_a = (const float*)d_in[2];
    const float* W_ih  = (const float*)d_in[3];
    const float* W_hh  = (const float*)d_in[4];
    const float* b_ih  = (const float*)d_in[5];
    const float* b_hh  = (const float*)d_in[6];
    const float* W_cls = (const float*)d_in[7];
    const float* b_cls = (const float*)d_in[8];
    float* out = (float*)d_out;

    float* ha = (float*)d_ws;                               // [B][T][H] fp32
    float* hc = ha + (size_t)BB * TT * HH;                  // [B][T][H] fp32
    float* G  = hc + (size_t)BB * TT * HH;                  // [2][V][384] fp32
    __hip_bfloat16* Whi = (__hip_bfloat16*)(G + (size_t)2 * VV * 384);
    __hip_bfloat16* Wlo = Whi + 384 * HH;
    unsigned short* WcH = (unsigned short*)(Wlo + 384 * HH);
    unsigned short* WcL = WcH + 112 * HH;

    prep_split<<<(384 * HH + 255) / 256, 256, 0, stream>>>(W_hh, Whi, Wlo);
    prep_wcls<<<(112 * HH + 255) / 256, 256, 0, stream>>>(W_cls, WcH, WcL);
    prep_G<<<dim3((VV + 31) / 32, 2), 256, 0, stream>>>(emb_a, emb_c, W_ih, b_ih, b_hh, G);
    gru_mfma<<<dim3(BB / 32, 2), 512, 0, stream>>>(ids, G, Whi, Wlo, b_hh, ha, hc);
    attn_cls_mfma<<<BB, 256, 0, stream>>>(ha, hc, WcH, WcL, b_cls, out);
}

// Round 4
// 648.435 us; speedup vs baseline: 6.1463x; 1.5340x over previous
//
#include <hip/hip_runtime.h>
#include <hip/hip_bf16.h>

#define BB 8192
#define TT 40
#define HH 128
#define CC 102
#define VV 4450

typedef __attribute__((ext_vector_type(8))) short short8;
typedef __attribute__((ext_vector_type(4))) float f4;

__device__ __forceinline__ float sigmoidf_(float x) { return 1.f / (1.f + __expf(-x)); }
__device__ __forceinline__ float tanhf_(float x) { float e = __expf(2.f * x); return 1.f - 2.f / (e + 1.f); }

__device__ __forceinline__ unsigned short f2bf(float x) {
    union { float f; unsigned u; } v; v.f = x;
    unsigned r = v.u + 0x7FFFu + ((v.u >> 16) & 1u);
    return (unsigned short)(r >> 16);
}
__device__ __forceinline__ float bf2f(unsigned short h) {
    union { float f; unsigned u; } v; v.u = ((unsigned)h) << 16; return v.f;
}
__device__ __forceinline__ short8 u4s8(uint4 v) { return *(short8*)&v; }

#define MFMA16(acc, a, b) acc = __builtin_amdgcn_mfma_f32_16x16x32_bf16(a, b, acc, 0, 0, 0)

// ---------- prep 1: split fp32 array into bf16 hi/lo ----------
__global__ __launch_bounds__(256) void prep_bf16split(const float* __restrict__ W,
                                                      unsigned short* __restrict__ hi,
                                                      unsigned short* __restrict__ lo, int n) {
    int i = blockIdx.x * 256 + threadIdx.x;
    if (i < n) {
        float x = W[i];
        unsigned short h = f2bf(x);
        hi[i] = h;
        lo[i] = f2bf(x - bf2f(h));
    }
}

// ---------- prep 1b: split W_cls into bf16 hi/lo, padded to 112 rows ----------
__global__ __launch_bounds__(256) void prep_wcls(const float* __restrict__ W,
                                                 unsigned short* __restrict__ hi,
                                                 unsigned short* __restrict__ lo) {
    int i = blockIdx.x * 256 + threadIdx.x;
    if (i < 112 * HH) {
        int r = i >> 7;
        float x = (r < CC) ? W[i] : 0.f;
        unsigned short h = f2bf(x);
        hi[i] = h;
        lo[i] = f2bf(x - bf2f(h));
    }
}

// ---------- prep 2: G[src][v][c] = emb[v] @ W_ih^T + biases, via MFMA ----------
// Block: 32 vocab rows x all 384 cols. 256 threads = 4 waves; wave w owns cols
// [w*96, w*96+96) = 6 n-tiles. bf16 hi/lo 3-term MFMA.
__global__ __launch_bounds__(256) void prep_G_mfma(
    const float* __restrict__ emb_a, const float* __restrict__ emb_c,
    const unsigned short* __restrict__ WihH, const unsigned short* __restrict__ WihL,
    const float* __restrict__ b_ih, const float* __restrict__ b_hh,
    float* __restrict__ G)
{
    __shared__ uint4 se[2][32][16];   // [hi/lo][row][swizzled 16B k-chunk]

    const int tid = threadIdx.x;
    const int src = blockIdx.y;
    const float* emb = src ? emb_c : emb_a;
    const int v0 = blockIdx.x * 32;

    const int lane = tid & 63;
    const int w = tid >> 6;
    const int mcol = lane & 15;
    const int quad = lane >> 4;

    // stage emb tile -> bf16 hi/lo (xor-swizzled: phys chunk = chunk ^ (row&15))
#pragma unroll
    for (int i = 0; i < 4; ++i) {
        int task = tid + 256 * i;       // 0..1023 = 32 rows x 32 float4
        int row = task >> 5, q = task & 31;
        int v = v0 + row;
        float4 x = make_float4(0.f, 0.f, 0.f, 0.f);
        if (v < VV) x = ((const float4*)(emb + (size_t)v * HH))[q];
        unsigned short h0 = f2bf(x.x), h1 = f2bf(x.y), h2 = f2bf(x.z), h3 = f2bf(x.w);
        unsigned short l0 = f2bf(x.x - bf2f(h0)), l1 = f2bf(x.y - bf2f(h1));
        unsigned short l2 = f2bf(x.z - bf2f(h2)), l3 = f2bf(x.w - bf2f(h3));
        uint2 Hw, Lw;
        Hw.x = (unsigned)h0 | ((unsigned)h1 << 16); Hw.y = (unsigned)h2 | ((unsigned)h3 << 16);
        Lw.x = (unsigned)l0 | ((unsigned)l1 << 16); Lw.y = (unsigned)l2 | ((unsigned)l3 << 16);
        int phys = (q >> 1) ^ (row & 15);
        ((uint2*)&se[0][row][phys])[q & 1] = Hw;
        ((uint2*)&se[1][row][phys])[q & 1] = Lw;
    }

    // per-lane biases for the 6 output col groups
    float bias[6];
#pragma unroll
    for (int n6 = 0; n6 < 6; ++n6) {
        int c = w * 96 + n6 * 16 + mcol;
        bias[n6] = b_ih[c] + (c < 256 ? b_hh[c] : 0.f);
    }

    f4 acc[2][6];
#pragma unroll
    for (int mt = 0; mt < 2; ++mt)
#pragma unroll
        for (int n6 = 0; n6 < 6; ++n6) acc[mt][n6] = (f4){0.f, 0.f, 0.f, 0.f};

    __syncthreads();

#pragma unroll
    for (int kk = 0; kk < 4; ++kk) {
        uint4 bH[6], bL[6];
#pragma unroll
        for (int n6 = 0; n6 < 6; ++n6) {
            int rowc = w * 96 + n6 * 16 + mcol;
            bH[n6] = *((const uint4*)WihH + rowc * 16 + kk * 4 + quad);
            bL[n6] = *((const uint4*)WihL + rowc * 16 + kk * 4 + quad);
        }
#pragma unroll
        for (int mt = 0; mt < 2; ++mt) {
            int m = mt * 16 + mcol;
            int phys = (kk * 4 + quad) ^ mcol;
            short8 ah = u4s8(se[0][m][phys]);
            short8 al = u4s8(se[1][m][phys]);
#pragma unroll
            for (int n6 = 0; n6 < 6; ++n6) {
                MFMA16(acc[mt][n6], ah, u4s8(bH[n6]));
                MFMA16(acc[mt][n6], ah, u4s8(bL[n6]));
                MFMA16(acc[mt][n6], al, u4s8(bH[n6]));
            }
        }
    }

    float* gout = G + (size_t)src * VV * 384;
#pragma unroll
    for (int mt = 0; mt < 2; ++mt)
#pragma unroll
        for (int r = 0; r < 4; ++r) {
            int m = mt * 16 + quad * 4 + r;
            int v = v0 + m;
            if (v < VV) {
#pragma unroll
                for (int n6 = 0; n6 < 6; ++n6) {
                    int c = w * 96 + n6 * 16 + mcol;
                    gout[(size_t)v * 384 + c] = acc[mt][n6][r] + bias[n6];
                }
            }
        }
}

// ---------- main GRU: M=32/block to avoid spills; G-gather prefetched ----------
__global__ __launch_bounds__(512, 2) void gru_mfma(
    const int* __restrict__ ids, const float* __restrict__ G,
    const __hip_bfloat16* __restrict__ Whi, const __hip_bfloat16* __restrict__ Wlo,
    const float* __restrict__ b_hh, float* __restrict__ ha, float* __restrict__ hc)
{
    __shared__ uint4 sh[2][2][32][16];
    __shared__ int sids[32 * TT];

    const int tid = threadIdx.x;
    const int src = blockIdx.y;
    const int b0 = blockIdx.x * 32;
    const float* Gs = G + (size_t)src * VV * 384;
    float* hout = src ? hc : ha;

    const int lane = tid & 63;
    const int w = tid >> 6;
    const int nc0 = w * 16;
    const int mcol = lane & 15;
    const int quad = lane >> 4;

    for (int idx = tid; idx < 32 * TT; idx += 512)
        sids[idx] = ids[b0 * TT + idx];

    {
        uint4 z; z.x = z.y = z.z = z.w = 0u;
        uint4* p = &sh[0][0][0][0];
        for (int idx = tid; idx < 2 * 32 * 16; idx += 512) p[idx] = z;
    }

    short8 bh[3][4], bl[3][4];
#pragma unroll
    for (int g = 0; g < 3; ++g)
#pragma unroll
        for (int kk = 0; kk < 4; ++kk) {
            int row = g * 128 + nc0 + mcol;
            uint4 vh = *((const uint4*)Whi + row * 16 + kk * 4 + quad);
            uint4 vl = *((const uint4*)Wlo + row * 16 + kk * 4 + quad);
            bh[g][kk] = u4s8(vh);
            bl[g][kk] = u4s8(vl);
        }

    const float bhn = b_hh[256 + nc0 + mcol];
    const float* gbase = Gs + nc0 + mcol;

    f4 hreg[2];
    hreg[0] = (f4){0.f, 0.f, 0.f, 0.f};
    hreg[1] = (f4){0.f, 0.f, 0.f, 0.f};

    __syncthreads();

    float gc[3][2][4];
#pragma unroll
    for (int mt = 0; mt < 2; ++mt)
#pragma unroll
        for (int reg = 0; reg < 4; ++reg) {
            int m = mt * 16 + quad * 4 + reg;
            int id = sids[m * TT + 0];
            const float* gp = gbase + (size_t)id * 384;
            gc[0][mt][reg] = gp[0];
            gc[1][mt][reg] = gp[128];
            gc[2][mt][reg] = gp[256];
        }

    int buf = 0;
#pragma unroll 1
    for (int t = 0; t < TT; ++t) {
        f4 acc[3][2];
#pragma unroll
        for (int g = 0; g < 3; ++g)
#pragma unroll
            for (int mt = 0; mt < 2; ++mt) acc[g][mt] = (f4){0.f, 0.f, 0.f, 0.f};

#pragma unroll
        for (int mt = 0; mt < 2; ++mt)
#pragma unroll
            for (int kk = 0; kk < 4; ++kk) {
                int m = mt * 16 + mcol;
                int phys = (kk * 4 + quad) ^ mcol;
                uint4 avh = sh[buf][0][m][phys];
                uint4 avl = sh[buf][1][m][phys];
                short8 ah = u4s8(avh), al = u4s8(avl);
#pragma unroll
                for (int g = 0; g < 3; ++g) {
                    MFMA16(acc[g][mt], ah, bh[g][kk]);
                    MFMA16(acc[g][mt], ah, bl[g][kk]);
                    MFMA16(acc[g][mt], al, bh[g][kk]);
                }
            }

        const int nbuf = buf ^ 1;
        const int j = nc0 + mcol;
        const int s_slot = j >> 3;
        const int jb = j & 7;
#pragma unroll
        for (int mt = 0; mt < 2; ++mt) {
#pragma unroll
            for (int reg = 0; reg < 4; ++reg) {
                float rr = sigmoidf_(acc[0][mt][reg] + gc[0][mt][reg]);
                float zz = sigmoidf_(acc[1][mt][reg] + gc[1][mt][reg]);
                float nn = tanhf_(gc[2][mt][reg] + rr * (acc[2][mt][reg] + bhn));
                float hv = (1.f - zz) * nn + zz * hreg[mt][reg];
                hreg[mt][reg] = hv;

                int m = mt * 16 + quad * 4 + reg;
                hout[((size_t)(b0 + m) * TT + t) * HH + j] = hv;

                unsigned short hb = f2bf(hv);
                unsigned short lb = f2bf(hv - bf2f(hb));
                int phys = s_slot ^ (m & 15);
                ((unsigned short*)&sh[nbuf][0][m][phys])[jb] = hb;
                ((unsigned short*)&sh[nbuf][1][m][phys])[jb] = lb;
            }
        }

        if (t < TT - 1) {
#pragma unroll
            for (int mt = 0; mt < 2; ++mt)
#pragma unroll
                for (int reg = 0; reg < 4; ++reg) {
                    int m = mt * 16 + quad * 4 + reg;
                    int id = sids[m * TT + t + 1];
                    const float* gp = gbase + (size_t)id * 384;
                    gc[0][mt][reg] = gp[0];
                    gc[1][mt][reg] = gp[128];
                    gc[2][mt][reg] = gp[256];
                }
        }
        __syncthreads();
        buf ^= 1;
    }
}

// ---------- attention + classifier, MFMA version ----------
#define AT_SHA     0
#define AT_SHA_LO  12288
#define AT_SHCT    24576
#define AT_SHCT_LO 40960
#define AT_SM      57344
#define AT_SW      66752
#define AT_SW_LO   72896
#define AT_PARTM   79040
#define AT_PARTD   79808
#define AT_SMX     80576
#define AT_SDI     80768
#define AT_TOTAL   80960

__global__ __launch_bounds__(256, 2) void attn_cls_mfma(
    const float* __restrict__ ha, const float* __restrict__ hc,
    const unsigned short* __restrict__ WcH, const unsigned short* __restrict__ WcL,
    const float* __restrict__ b_cls, float* __restrict__ out)
{
    __shared__ __attribute__((aligned(16))) char smem[AT_TOTAL];
    const int tid = threadIdx.x;
    const int lane = tid & 63;
    const int w = tid >> 6;
    const int quad = lane >> 4;
    const int col = lane & 15;
    const size_t b = blockIdx.x;

    float* sm    = (float*)(smem + AT_SM);
    float* slog  = (float*)(smem + AT_SM);
    float* partM = (float*)(smem + AT_PARTM);
    float* partD = (float*)(smem + AT_PARTD);
    float* sMX   = (float*)(smem + AT_SMX);
    float* sDI   = (float*)(smem + AT_SDI);

    const int ntc0 = (w < 3) ? w : 3;
    const int ntc1 = (w < 3) ? w + 4 : 3;
    uint4 bw[2][4][2];
    float bcv[2];
    {
        int nts[2] = {ntc0, ntc1};
#pragma unroll
        for (int which = 0; which < 2; ++which) {
            int row = nts[which] * 16 + col;
#pragma unroll
            for (int kk = 0; kk < 4; ++kk) {
                bw[which][kk][0] = *((const uint4*)WcH + row * 16 + kk * 4 + quad);
                bw[which][kk][1] = *((const uint4*)WcL + row * 16 + kk * 4 + quad);
            }
            bcv[which] = (row < CC) ? b_cls[row] : 0.f;
        }
    }

    {
        const float4* hab = (const float4*)(ha + b * TT * HH);
#pragma unroll
        for (int i = 0; i < 5; ++i) {
            int f4i = tid + 256 * i;
            int row = f4i >> 5, q = f4i & 31;
            float4 v = hab[f4i];
            unsigned short h0 = f2bf(v.x), h1 = f2bf(v.y), h2 = f2bf(v.z), h3 = f2bf(v.w);
            unsigned short l0 = f2bf(v.x - bf2f(h0)), l1 = f2bf(v.y - bf2f(h1));
            unsigned short l2 = f2bf(v.z - bf2f(h2)), l3 = f2bf(v.w - bf2f(h3));
            uint2 Hw, Lw;
            Hw.x = (unsigned)h0 | ((unsigned)h1 << 16); Hw.y = (unsigned)h2 | ((unsigned)h3 << 16);
            Lw.x = (unsigned)l0 | ((unsigned)l1 << 16); Lw.y = (unsigned)l2 | ((unsigned)l3 << 16);
            int phys = (q >> 1) ^ (row & 15);
            int off = row * 256 + phys * 16 + (q & 1) * 8;
            *(uint2*)(smem + AT_SHA + off) = Hw;
            *(uint2*)(smem + AT_SHA_LO + off) = Lw;
        }
        if (tid < 128) {
            int row = 40 + (tid >> 4), c = tid & 15;
            uint4 z; z.x = z.y = z.z = z.w = 0u;
            *(uint4*)(smem + AT_SHA + row * 256 + c * 16) = z;
            *(uint4*)(smem + AT_SHA_LO + row * 256 + c * 16) = z;
        }
        const float* hcb = hc + b * TT * HH;
        for (int task = tid; task < 640; task += 256) {
            int h = task & 127, c = task >> 7;
            unsigned short H8[8], L8[8];
#pragma unroll
            for (int jj = 0; jj < 8; ++jj) {
                float x = hcb[(c * 8 + jj) * HH + h];
                H8[jj] = f2bf(x);
                L8[jj] = f2bf(x - bf2f(H8[jj]));
            }
            uint4 Hq, Lq;
            Hq.x = (unsigned)H8[0] | ((unsigned)H8[1] << 16); Hq.y = (unsigned)H8[2] | ((unsigned)H8[3] << 16);
            Hq.z = (unsigned)H8[4] | ((unsigned)H8[5] << 16); Hq.w = (unsigned)H8[6] | ((unsigned)H8[7] << 16);
            Lq.x = (unsigned)L8[0] | ((unsigned)L8[1] << 16); Lq.y = (unsigned)L8[2] | ((unsigned)L8[3] << 16);
            Lq.z = (unsigned)L8[4] | ((unsigned)L8[5] << 16); Lq.w = (unsigned)L8[6] | ((unsigned)L8[7] << 16);
            int phys = c ^ (h & 7);
            *(uint4*)(smem + AT_SHCT + h * 128 + phys * 16) = Hq;
            *(uint4*)(smem + AT_SHCT_LO + h * 128 + phys * 16) = Lq;
        }
        for (int task = tid; task < 384; task += 256) {
            int h = task & 127, c = 5 + (task >> 7);
            int phys = c ^ (h & 7);
            uint4 z; z.x = z.y = z.z = z.w = 0u;
            *(uint4*)(smem + AT_SHCT + h * 128 + phys * 16) = z;
            *(uint4*)(smem + AT_SHCT_LO + h * 128 + phys * 16) = z;
        }
    }
    __syncthreads();

    if (w < 3) {
        const int mt = w;
        uint4 aH[4], aL[4];
#pragma unroll
        for (int kk = 0; kk < 4; ++kk) {
            int phys = (kk * 4 + quad) ^ col;
            int off = (mt * 16 + col) * 256 + phys * 16;
            aH[kk] = *(uint4*)(smem + AT_SHA + off);
            aL[kk] = *(uint4*)(smem + AT_SHA_LO + off);
        }
        f4 acc[3];
#pragma unroll
        for (int nt = 0; nt < 3; ++nt) acc[nt] = (f4){0.f, 0.f, 0.f, 0.f};
#pragma unroll
        for (int kk = 0; kk < 4; ++kk) {
            short8 ah = u4s8(aH[kk]), al = u4s8(aL[kk]);
#pragma unroll
            for (int nt = 0; nt < 3; ++nt) {
                int phys = (kk * 4 + quad) ^ col;
                int off = (nt * 16 + col) * 256 + phys * 16;
                short8 bH = u4s8(*(uint4*)(smem + AT_SHA + off));
                short8 bL = u4s8(*(uint4*)(smem + AT_SHA_LO + off));
                MFMA16(acc[nt], ah, bH);
                MFMA16(acc[nt], ah, bL);
                MFMA16(acc[nt], al, bH);
            }
        }
#pragma unroll
        for (int nt = 0; nt < 3; ++nt)
#pragma unroll
            for (int r = 0; r < 4; ++r)
                sm[(mt * 16 + quad * 4 + r) * 49 + nt * 16 + col] = acc[nt][r];
    }
    __syncthreads();

    if (tid < 160) {
        int t = tid >> 2, p = tid & 3;
        const float* row = sm + t * 49 + p * 10;
        float M = row[0];
#pragma unroll
        for (int i = 1; i < 10; ++i) M = fmaxf(M, row[i]);
        float D = 0.f;
#pragma unroll
        for (int i = 0; i < 10; ++i) D += __expf(row[i] - M);
        partM[t * 4 + p] = M;
        partD[t * 4 + p] = D;
    }
    __syncthreads();
    if (tid < 40) {
        float M = partM[tid * 4];
        M = fmaxf(M, partM[tid * 4 + 1]); M = fmaxf(M, partM[tid * 4 + 2]); M = fmaxf(M, partM[tid * 4 + 3]);
        float D = 0.f;
#pragma unroll
        for (int p = 0; p < 4; ++p) D += partD[tid * 4 + p] * __expf(partM[tid * 4 + p] - M);
        sMX[tid] = M;
        sDI[tid] = 1.f / D;
    }
    __syncthreads();

    for (int task = tid; task < 384; task += 256) {
        int s = task >> 3, c = task & 7;
        uint4 Hq, Lq;
        if (c >= 5) {
            Hq.x = Hq.y = Hq.z = Hq.w = 0u; Lq = Hq;
        } else {
            const float* srow = sm + s * 49 + c * 8;
            unsigned short H8[8], L8[8];
#pragma unroll
            for (int jj = 0; jj < 8; ++jj) {
                int t = c * 8 + jj;
                float wv = __expf(srow[jj] - sMX[t]) * sDI[t];
                H8[jj] = f2bf(wv);
                L8[jj] = f2bf(wv - bf2f(H8[jj]));
            }
            Hq.x = (unsigned)H8[0] | ((unsigned)H8[1] << 16); Hq.y = (unsigned)H8[2] | ((unsigned)H8[3] << 16);
            Hq.z = (unsigned)H8[4] | ((unsigned)H8[5] << 16); Hq.w = (unsigned)H8[6] | ((unsigned)H8[7] << 16);
            Lq.x = (unsigned)L8[0] | ((unsigned)L8[1] << 16); Lq.y = (unsigned)L8[2] | ((unsigned)L8[3] << 16);
            Lq.z = (unsigned)L8[4] | ((unsigned)L8[5] << 16); Lq.w = (unsigned)L8[6] | ((unsigned)L8[7] << 16);
        }
        int phys = c ^ (s & 7);
        *(uint4*)(smem + AT_SW + s * 128 + phys * 16) = Hq;
        *(uint4*)(smem + AT_SW_LO + s * 128 + phys * 16) = Lq;
    }
    __syncthreads();

    {
        uint4 aH[3][2], aL[3][2];
#pragma unroll
        for (int mt = 0; mt < 3; ++mt)
#pragma unroll
            for (int kk = 0; kk < 2; ++kk) {
                int s = mt * 16 + col;
                int phys = (kk * 4 + quad) ^ (s & 7);
                aH[mt][kk] = *(uint4*)(smem + AT_SW + s * 128 + phys * 16);
                aL[mt][kk] = *(uint4*)(smem + AT_SW_LO + s * 128 + phys * 16);
            }
        f4 acc[3][2];
#pragma unroll
        for (int mt = 0; mt < 3; ++mt) { acc[mt][0] = (f4){0,0,0,0}; acc[mt][1] = (f4){0,0,0,0}; }
#pragma unroll
        for (int which = 0; which < 2; ++which) {
            int nt = w + which * 4;
            int hrow = nt * 16 + col;
#pragma unroll
            for (int kk = 0; kk < 2; ++kk) {
                int phys = (kk * 4 + quad) ^ (hrow & 7);
                short8 bH = u4s8(*(uint4*)(smem + AT_SHCT + hrow * 128 + phys * 16));
                short8 bL = u4s8(*(uint4*)(smem + AT_SHCT_LO + hrow * 128 + phys * 16));
#pragma unroll
                for (int mt = 0; mt < 3; ++mt) {
                    short8 ah = u4s8(aH[mt][kk]), al = u4s8(aL[mt][kk]);
                    MFMA16(acc[mt][which], ah, bH);
                    MFMA16(acc[mt][which], ah, bL);
                    MFMA16(acc[mt][which], al, bH);
                }
            }
        }
        __syncthreads();
#pragma unroll
        for (int which = 0; which < 2; ++which) {
            int h = (w + which * 4) * 16 + col;
            int chunk = h >> 3, hb7 = (h & 7) * 2;
#pragma unroll
            for (int mt = 0; mt < 3; ++mt)
#pragma unroll
                for (int r = 0; r < 4; ++r) {
                    float v = acc[mt][which][r];
                    int s = mt * 16 + quad * 4 + r;
                    unsigned short hbv = f2bf(v);
                    unsigned short lbv = f2bf(v - bf2f(hbv));
                    int phys = chunk ^ (s & 15);
                    *(unsigned short*)(smem + AT_SHA + s * 256 + phys * 16 + hb7) = hbv;
                    *(unsigned short*)(smem + AT_SHA_LO + s * 256 + phys * 16 + hb7) = lbv;
                }
        }
    }
    __syncthreads();

    {
        f4 acc[3][2];
#pragma unroll
        for (int mt = 0; mt < 3; ++mt) { acc[mt][0] = (f4){0,0,0,0}; acc[mt][1] = (f4){0,0,0,0}; }
#pragma unroll
        for (int kk = 0; kk < 4; ++kk)
#pragma unroll
            for (int mt = 0; mt < 3; ++mt) {
                int s = mt * 16 + col;
                int phys = (kk * 4 + quad) ^ (s & 15);
                short8 ah = u4s8(*(uint4*)(smem + AT_SHA + s * 256 + phys * 16));
                short8 al = u4s8(*(uint4*)(smem + AT_SHA_LO + s * 256 + phys * 16));
#pragma unroll
                for (int which = 0; which < 2; ++which) {
                    MFMA16(acc[mt][which], ah, u4s8(bw[which][kk][0]));
                    MFMA16(acc[mt][which], ah, u4s8(bw[which][kk][1]));
                    MFMA16(acc[mt][which], al, u4s8(bw[which][kk][0]));
                }
            }
        __syncthreads();
        int nts[2] = {ntc0, ntc1};
#pragma unroll
        for (int which = 0; which < 2; ++which) {
            int c = nts[which] * 16 + col;
#pragma unroll
            for (int mt = 0; mt < 3; ++mt)
#pragma unroll
                for (int r = 0; r < 4; ++r)
                    slog[(mt * 16 + quad * 4 + r) * 113 + c] = acc[mt][which][r] + bcv[which];
        }
    }
    __syncthreads();

    if (tid < 160) {
        int s = tid >> 2, p = tid & 3;
        int c0 = p * 26;
        int c1 = (c0 + 26 < CC) ? c0 + 26 : CC;
        const float* row = slog + s * 113;
        float M = row[c0];
        for (int c = c0 + 1; c < c1; ++c) M = fmaxf(M, row[c]);
        float D = 0.f;
        for (int c = c0; c < c1; ++c) D += __expf(row[c] - M);
        partM[s * 4 + p] = M;
        partD[s * 4 + p] = D;
    }
    __syncthreads();
    if (tid < 40) {
        float M = partM[tid * 4];
        M = fmaxf(M, partM[tid * 4 + 1]); M = fmaxf(M, partM[tid * 4 + 2]); M = fmaxf(M, partM[tid * 4 + 3]);
        float D = 0.f;
#pragma unroll
        for (int p = 0; p < 4; ++p) D += partD[tid * 4 + p] * __expf(partM[tid * 4 + p] - M);
        sMX[tid] = M;
        sDI[tid] = 1.f / D;
    }
    __syncthreads();

    {
        int c = tid & 127, s0 = tid >> 7;
        if (c < CC) {
            float* ob = out + b * TT * CC;
            for (int s = s0; s < TT; s += 2)
                ob[s * CC + c] = __expf(slog[s * 113 + c] - sMX[s]) * sDI[s];
        }
    }
}

extern "C" void kernel_launch(void* const* d_in, const int* in_sizes, int n_in,
                              void* d_out, int out_size, void* d_ws, size_t ws_size,
                              hipStream_t stream) {
    const int*   ids   = (const int*)d_in[0];
    const float* emb_c = (const float*)d_in[1];
    const float* emb_a = (const float*)d_in[2];
    const float* W_ih  = (const float*)d_in[3];
    const float* W_hh  = (const float*)d_in[4];
    const float* b_ih  = (const float*)d_in[5];
    const float* b_hh  = (const float*)d_in[6];
    const float* W_cls = (const float*)d_in[7];
    const float* b_cls = (const float*)d_in[8];
    float* out = (float*)d_out;

    float* ha = (float*)d_ws;                               // [B][T][H] fp32
    float* hc = ha + (size_t)BB * TT * HH;                  // [B][T][H] fp32
    float* G  = hc + (size_t)BB * TT * HH;                  // [2][V][384] fp32
    __hip_bfloat16* Whi = (__hip_bfloat16*)(G + (size_t)2 * VV * 384);
    __hip_bfloat16* Wlo = Whi + 384 * HH;
    unsigned short* WcH = (unsigned short*)(Wlo + 384 * HH);
    unsigned short* WcL = WcH + 112 * HH;
    unsigned short* WihH = WcL + 112 * HH;
    unsigned short* WihL = WihH + 384 * HH;

    prep_bf16split<<<(384 * HH + 255) / 256, 256, 0, stream>>>(W_hh, (unsigned short*)Whi, (unsigned short*)Wlo, 384 * HH);
    prep_bf16split<<<(384 * HH + 255) / 256, 256, 0, stream>>>(W_ih, WihH, WihL, 384 * HH);
    prep_wcls<<<(112 * HH + 255) / 256, 256, 0, stream>>>(W_cls, WcH, WcL);
    prep_G_mfma<<<dim3((VV + 31) / 32, 2), 256, 0, stream>>>(emb_a, emb_c, WihH, WihL, b_ih, b_hh, G);
    gru_mfma<<<dim3(BB / 32, 2), 512, 0, stream>>>(ids, G, Whi, Wlo, b_hh, ha, hc);
    attn_cls_mfma<<<BB, 256, 0, stream>>>(ha, hc, WcH, WcL, b_cls, out);
}